// Round 1
// 348.924 us; speedup vs baseline: 1.0377x; 1.0377x over previous
//
#include <hip/hip_runtime.h>
#include <hip/hip_fp16.h>

#define N_NODES 50000
#define N_FEAT  128
#define HID     64
#define N_EDGES 800000
#define N_GRAPHS 64
#define MAXDEG  64
#define BN_EPS  1e-5f
#define NB256(n) (((n) + 255) / 256)

// ---------------- zero fill counters ----------------
__global__ __launch_bounds__(256) void k_zero(int* fill) {
    int i = blockIdx.x * 256 + threadIdx.x;
    if (i < N_NODES) fill[i] = 0;
}

// ---------------- fused dual-GEMM with piggybacked edge placement ----------------
// 2500 blocks x 20 nodes: stage x ONCE, compute BOTH x@W_in^T (fp32 h) and
// x@W1^T (fp16 g16). Per k4: 2 W reads + 5 x reads feed 40 FMAs (was 4 FMAs
// per x read with split GEMMs). LDS 26.9 KB -> 6 blocks/CU (was 37.4 KB -> 4).
#define GE_NB 2500
__global__ __launch_bounds__(256) void k_gemmedge(const int* __restrict__ ei,
                                                  int* fill, unsigned short* __restrict__ colp,
                                                  const float* __restrict__ x,
                                                  const float* __restrict__ W_in,
                                                  const float* __restrict__ W1,
                                                  float* __restrict__ h,
                                                  __half* __restrict__ g16) {
    __shared__ float4 Wt[2][8 * 65];   // 8 k4-slices of both W, stride 65 (conflict-free)
    __shared__ float4 xs[20 * 32];     // 20 node rows of x
    const int bid = blockIdx.x;
    const int t = threadIdx.x;

    // edge slice: issue atomics now, consume results after the GEMM
    const int ebase = bid * 320;
    int s1 = ei[ebase + t];
    int d1 = ei[N_EDGES + ebase + t];
    int k1 = atomicAdd(&fill[d1], 1);
    int s2 = 0, d2 = 0, k2 = MAXDEG;
    if (t < 64) {
        s2 = ei[ebase + 256 + t];
        d2 = ei[N_EDGES + ebase + 256 + t];
        k2 = atomicAdd(&fill[d2], 1);
    }

    const int base = bid * 20;
    const float4* xv = (const float4*)(x + (long long)base * N_FEAT);
    for (int i = t; i < 20 * 32; i += 256) xs[i] = xv[i];

    const float4* W0v = (const float4*)W_in;
    const float4* W1v = (const float4*)W1;
    const int hh = t & 63;
    const int ng = t >> 6;
    float4 a0[5], a1[5];
#pragma unroll
    for (int j = 0; j < 5; ++j) {
        a0[j] = make_float4(0.f, 0.f, 0.f, 0.f);
        a1[j] = make_float4(0.f, 0.f, 0.f, 0.f);
    }

    for (int c = 0; c < 32; c += 8) {
        __syncthreads();  // WAR on Wt (also orders xs staging before first MAC)
        for (int i = t; i < 64 * 8; i += 256) {
            int h2 = i >> 3, k4 = i & 7;
            Wt[0][k4 * 65 + h2] = W0v[h2 * 32 + c + k4];
            Wt[1][k4 * 65 + h2] = W1v[h2 * 32 + c + k4];
        }
        __syncthreads();
#pragma unroll
        for (int k4 = 0; k4 < 8; ++k4) {
            float4 w0 = Wt[0][k4 * 65 + hh];
            float4 w1 = Wt[1][k4 * 65 + hh];
#pragma unroll
            for (int j = 0; j < 5; ++j) {
                float4 xx = xs[(ng + 4 * j) * 32 + c + k4];   // wave-broadcast
                a0[j].x += w0.x * xx.x; a0[j].y += w0.y * xx.y;
                a0[j].z += w0.z * xx.z; a0[j].w += w0.w * xx.w;
                a1[j].x += w1.x * xx.x; a1[j].y += w1.y * xx.y;
                a1[j].z += w1.z * xx.z; a1[j].w += w1.w * xx.w;
            }
        }
    }
#pragma unroll
    for (int j = 0; j < 5; ++j) {
        int node = base + ng + 4 * j;
        h[node * HID + hh]   = a0[j].x + a0[j].y + a0[j].z + a0[j].w;
        g16[node * HID + hh] = __float2half(a1[j].x + a1[j].y + a1[j].z + a1[j].w);
    }

    // deferred stores: atomic results long since returned
    if (k1 < MAXDEG) colp[d1 * MAXDEG + k1] = (unsigned short)s1;
    if (k2 < MAXDEG) colp[d2 * MAXDEG + k2] = (unsigned short)s2;
}

// ---- fp16 row accumulate, scaled (FMA — same cost as plain add) ----
__device__ __forceinline__ void acc8s(const uint4 r, float* a, float s) {
    float2 f0 = __half22float2(*(const __half2*)&r.x);
    float2 f1 = __half22float2(*(const __half2*)&r.y);
    float2 f2 = __half22float2(*(const __half2*)&r.z);
    float2 f3 = __half22float2(*(const __half2*)&r.w);
    a[0] += s * f0.x; a[1] += s * f0.y; a[2] += s * f1.x; a[3] += s * f1.y;
    a[4] += s * f2.x; a[5] += s * f2.y; a[6] += s * f3.x; a[7] += s * f3.y;
}

// ------ fused gather(+BN/ReLU/res) [+ per-wave GEMM], TWO nodes per wave ------
// 6250 blocks, 8 nodes/block, 2 independent gather chains per wave (doubles
// outstanding loads per wave slot). Col prefetch: lanes 0-31 carry node A's
// cols, 32-63 node B's; rounds alternate A/B via shfl. Rare deg>32 handled by
// a wave-uniform tail reading colp directly. Wave-decoupled (only barrier is
// after Wt staging).
template <bool NSCALE, bool DOGEMM>
__global__ __launch_bounds__(256) void k_gather_fused(const __half* __restrict__ gin,
                                                      const unsigned short* __restrict__ colp,
                                                      const int* __restrict__ fill,
                                                      const float* __restrict__ b,
                                                      const float* __restrict__ gamma,
                                                      const float* __restrict__ beta,
                                                      const float* __restrict__ mean,
                                                      const float* __restrict__ var,
                                                      const float4* __restrict__ res4,
                                                      float4* __restrict__ h4,
                                                      const float* __restrict__ W,
                                                      __half* __restrict__ gout) {
    __shared__ float4 Wt[DOGEMM ? 16 * 65 : 1];
    __shared__ float4 hrow[DOGEMM ? 8 * 16 : 1];

    const int t = threadIdx.x;
    const int wv = t >> 6;
    const int lane = t & 63;
    const int hh8 = lane & 7;
    const int sub = lane >> 3;
    const int nA = blockIdx.x * 8 + wv * 2;
    const int nB = nA + 1;

    if (DOGEMM) {
        const float4* Wv = (const float4*)W;
        for (int i = t; i < HID * 16; i += 256) {
            int h2 = i >> 4, k4 = i & 15;
            Wt[k4 * 65 + h2] = Wv[i];
        }
        __syncthreads();   // only block barrier: Wt visible before any use
    }

    const uint4* gv = (const uint4*)gin;  // row = 8 x uint4 (128 B)
    int flA = fill[nA], flB = fill[nB];
    int degA = flA < MAXDEG ? flA : MAXDEG;
    int degB = flB < MAXDEG ? flB : MAXDEG;

    // col prefetch: lanes 0-31 -> A cols 0-31, lanes 32-63 -> B cols 0-31
    const int myn   = (lane < 32) ? nA : nB;
    const int myj   = lane & 31;
    const int mydeg = (lane < 32) ? degA : degB;
    const bool valid = (myj < mydeg);
    int call = valid ? (int)colp[myn * MAXDEG + myj] : myn;   // pad -> own row
    float sall;
    if (NSCALE) sall = valid ? rsqrtf((float)fill[call] + 1.0f) : 0.0f;
    else        sall = valid ? 1.0f : 0.0f;

    float aA[8], aB[8];
#pragma unroll
    for (int i = 0; i < 8; ++i) { aA[i] = 0.f; aB[i] = 0.f; }

    int dA32 = degA < 32 ? degA : 32;
    int dB32 = degB < 32 ? degB : 32;
    int nra = (dA32 + 7) >> 3;
    int nrb = (dB32 + 7) >> 3;
    int nr = nra > nrb ? nra : nrb;
#pragma unroll 4
    for (int r = 0; r < nr; ++r) {
        int j = r * 8 + sub;
        if (r < nra) {                                  // wave-uniform branch
            int c = __shfl(call, j);
            float s = __shfl(sall, j);
            acc8s(gv[c * 8 + hh8], aA, s);
        }
        if (r < nrb) {
            int c = __shfl(call, 32 + j);
            float s = __shfl(sall, 32 + j);
            acc8s(gv[c * 8 + hh8], aB, s);
        }
    }
    // rare overflow (deg > 32): wave-uniform tail, direct colp loads
    if (degA > 32) {
        for (int j = 32 + sub; j < degA; j += 8) {
            int c = (int)colp[nA * MAXDEG + j];
            float s = NSCALE ? rsqrtf((float)fill[c] + 1.0f) : 1.0f;
            acc8s(gv[c * 8 + hh8], aA, s);
        }
    }
    if (degB > 32) {
        for (int j = 32 + sub; j < degB; j += 8) {
            int c = (int)colp[nB * MAXDEG + j];
            float s = NSCALE ? rsqrtf((float)fill[c] + 1.0f) : 1.0f;
            acc8s(gv[c * 8 + hh8], aB, s);
        }
    }

#pragma unroll
    for (int m = 8; m <= 32; m <<= 1) {
#pragma unroll
        for (int i = 0; i < 8; ++i) { aA[i] += __shfl_xor(aA[i], m); aB[i] += __shfl_xor(aB[i], m); }
    }
    // allreduce complete: every lane holds the full 8-feature partials

    const float diA = rsqrtf((float)flA + 1.0f);
    const float diB = rsqrtf((float)flB + 1.0f);
    acc8s(gv[nA * 8 + hh8], aA, NSCALE ? diA : 1.0f);  // self loops
    acc8s(gv[nB * 8 + hh8], aB, NSCALE ? diB : 1.0f);

    float4 b0 = ((const float4*)b)[hh8 * 2],     b1 = ((const float4*)b)[hh8 * 2 + 1];
    float4 g0 = ((const float4*)gamma)[hh8 * 2], g1 = ((const float4*)gamma)[hh8 * 2 + 1];
    float4 e0 = ((const float4*)beta)[hh8 * 2],  e1 = ((const float4*)beta)[hh8 * 2 + 1];
    float4 m0 = ((const float4*)mean)[hh8 * 2],  m1 = ((const float4*)mean)[hh8 * 2 + 1];
    float4 v0 = ((const float4*)var)[hh8 * 2],   v1 = ((const float4*)var)[hh8 * 2 + 1];

    float bb[8] = {b0.x, b0.y, b0.z, b0.w, b1.x, b1.y, b1.z, b1.w};
    float gg[8] = {g0.x, g0.y, g0.z, g0.w, g1.x, g1.y, g1.z, g1.w};
    float ee[8] = {e0.x, e0.y, e0.z, e0.w, e1.x, e1.y, e1.z, e1.w};
    float mm[8] = {m0.x, m0.y, m0.z, m0.w, m1.x, m1.y, m1.z, m1.w};
    float vv[8] = {v0.x, v0.y, v0.z, v0.w, v1.x, v1.y, v1.z, v1.w};

    float oA[8], oB[8];
#pragma unroll
    for (int i = 0; i < 8; ++i) {
        float sc = gg[i] * rsqrtf(vv[i] + BN_EPS);
        float vA = (aA[i] * diA + bb[i] - mm[i]) * sc + ee[i];
        float vB = (aB[i] * diB + bb[i] - mm[i]) * sc + ee[i];
        oA[i] = fmaxf(vA, 0.f);
        oB[i] = fmaxf(vB, 0.f);
    }
    if (res4) {
        float4 rA0 = res4[nA * 16 + hh8 * 2], rA1 = res4[nA * 16 + hh8 * 2 + 1];
        float4 rB0 = res4[nB * 16 + hh8 * 2], rB1 = res4[nB * 16 + hh8 * 2 + 1];
        oA[0] += rA0.x; oA[1] += rA0.y; oA[2] += rA0.z; oA[3] += rA0.w;
        oA[4] += rA1.x; oA[5] += rA1.y; oA[6] += rA1.z; oA[7] += rA1.w;
        oB[0] += rB0.x; oB[1] += rB0.y; oB[2] += rB0.z; oB[3] += rB0.w;
        oB[4] += rB1.x; oB[5] += rB1.y; oB[6] += rB1.z; oB[7] += rB1.w;
    }
    float4 loA = make_float4(oA[0], oA[1], oA[2], oA[3]);
    float4 hiA = make_float4(oA[4], oA[5], oA[6], oA[7]);
    float4 loB = make_float4(oB[0], oB[1], oB[2], oB[3]);
    float4 hiB = make_float4(oB[4], oB[5], oB[6], oB[7]);
    if (sub == 0) {
        h4[nA * 16 + hh8 * 2]     = loA;
        h4[nA * 16 + hh8 * 2 + 1] = hiA;
        h4[nB * 16 + hh8 * 2]     = loB;
        h4[nB * 16 + hh8 * 2 + 1] = hiB;
        if (DOGEMM) {
            hrow[(wv * 2) * 16 + hh8 * 2]         = loA;
            hrow[(wv * 2) * 16 + hh8 * 2 + 1]     = hiA;
            hrow[(wv * 2 + 1) * 16 + hh8 * 2]     = loB;
            hrow[(wv * 2 + 1) * 16 + hh8 * 2 + 1] = hiB;
        }
    }

    if (DOGEMM) {
        // same-wave LDS write->read: in-order, no barrier needed
        const int hh = lane;
        float4 accA = make_float4(0.f, 0.f, 0.f, 0.f);
        float4 accB = make_float4(0.f, 0.f, 0.f, 0.f);
#pragma unroll
        for (int k4 = 0; k4 < 16; ++k4) {
            float4 w = Wt[k4 * 65 + hh];
            float4 hA = hrow[(wv * 2) * 16 + k4];      // wave-broadcast (free)
            float4 hB = hrow[(wv * 2 + 1) * 16 + k4];
            accA.x += hA.x * w.x; accA.y += hA.y * w.y;
            accA.z += hA.z * w.z; accA.w += hA.w * w.w;
            accB.x += hB.x * w.x; accB.y += hB.y * w.y;
            accB.z += hB.z * w.z; accB.w += hB.w * w.w;
        }
        gout[nA * HID + hh] = __float2half((accA.x + accA.y + accA.z + accA.w) * diA);
        gout[nB * HID + hh] = __float2half((accB.x + accB.y + accB.z + accB.w) * diB);
    }
}

// ---------------- pool + final linear: one 1024-thread block per graph ----------------
__device__ __forceinline__ int lowerb(const int* __restrict__ b, int val) {
    int lo = 0, hi = N_NODES;
    while (lo < hi) {
        int mid = (lo + hi) >> 1;
        if (b[mid] < val) lo = mid + 1; else hi = mid;
    }
    return lo;
}

__global__ __launch_bounds__(1024) void k_poolfinal(const float* __restrict__ h,
                                                    const int* __restrict__ batch,
                                                    const float* __restrict__ lin_w,
                                                    const float* __restrict__ lin_b,
                                                    float* __restrict__ out) {
    __shared__ float red[16][HID];
    int g = blockIdx.x;
    int w = threadIdx.x >> 6;
    int hh = threadIdx.x & 63;
    int start = lowerb(batch, g);
    int end = lowerb(batch, g + 1);
    int len = end - start;
    float acc = 0.f;
    for (int n = start + w; n < end; n += 16) acc += h[n * HID + hh];
    red[w][hh] = acc;
    __syncthreads();
    if (w == 0) {
        float s = 0.f;
#pragma unroll
        for (int i = 0; i < 16; ++i) s += red[i][hh];
        float c = fmaxf((float)len, 1.0f);
        float v = (s / c) * lin_w[hh];
#pragma unroll
        for (int off = 32; off > 0; off >>= 1) v += __shfl_down(v, off);
        if (hh == 0) out[g] = v + lin_b[0];
    }
}

extern "C" void kernel_launch(void* const* d_in, const int* in_sizes, int n_in,
                              void* d_out, int out_size, void* d_ws, size_t ws_size,
                              hipStream_t stream) {
    const float* x     = (const float*)d_in[0];
    const int*   ei    = (const int*)d_in[1];
    const int*   batch = (const int*)d_in[2];
    const float* W_in  = (const float*)d_in[3];
    const float* W1    = (const float*)d_in[4];
    const float* b1    = (const float*)d_in[5];
    const float* Ws    = (const float*)d_in[6];
    const float* bs_   = (const float*)d_in[7];
    const float* bn_g  = (const float*)d_in[8];
    const float* bn_b  = (const float*)d_in[9];
    const float* bn_m  = (const float*)d_in[10];
    const float* bn_v  = (const float*)d_in[11];
    const float* lin_w = (const float*)d_in[12];
    const float* lin_b = (const float*)d_in[13];
    float* out = (float*)d_out;

    char* q = (char*)d_ws;
    int*            fill = (int*)q;             q += (size_t)50048 * 4;
    unsigned short* colp = (unsigned short*)q;  q += (size_t)N_NODES * MAXDEG * 2;
    __half*         g16a = (__half*)q;          q += (size_t)N_NODES * HID * 2;
    __half*         g16b = (__half*)q;          q += (size_t)N_NODES * HID * 2;
    float*          h    = (float*)q;           q += (size_t)N_NODES * HID * 4;

    const int NB_N   = NB256(N_NODES);
    const int NB_GA2 = N_NODES / 8;  // 6250
    float4* h4 = (float4*)h;

    // zero fill, then fused dual-GEMM (identity + layer-1) with deferred-store edge placement
    k_zero<<<NB_N, 256, 0, stream>>>(fill);
    k_gemmedge<<<GE_NB, 256, 0, stream>>>(ei, fill, colp, x, W_in, W1, h, g16a);

    // layer 1: gather (per-source dinv; g16a unscaled) + fused gemm for layer 2
    k_gather_fused<true, true><<<NB_GA2, 256, 0, stream>>>(
        g16a, colp, fill, b1, bn_g, bn_b, bn_m, bn_v,
        (const float4*)h, h4, Ws + 0 * HID * HID, g16b);

    // layers 2-4: gather (pre-scaled g16) + fused gemm for next layer
    k_gather_fused<false, true><<<NB_GA2, 256, 0, stream>>>(
        g16b, colp, fill, bs_ + 0 * HID,
        bn_g + 1 * HID, bn_b + 1 * HID, bn_m + 1 * HID, bn_v + 1 * HID,
        (const float4*)h, h4, Ws + 1 * HID * HID, g16a);

    k_gather_fused<false, true><<<NB_GA2, 256, 0, stream>>>(
        g16a, colp, fill, bs_ + 1 * HID,
        bn_g + 2 * HID, bn_b + 2 * HID, bn_m + 2 * HID, bn_v + 2 * HID,
        (const float4*)h, h4, Ws + 2 * HID * HID, g16b);

    k_gather_fused<false, true><<<NB_GA2, 256, 0, stream>>>(
        g16b, colp, fill, bs_ + 2 * HID,
        bn_g + 3 * HID, bn_b + 3 * HID, bn_m + 3 * HID, bn_v + 3 * HID,
        (const float4*)h, h4, Ws + 3 * HID * HID, g16a);

    // layer 5: gather only (no residual, no next gemm)
    k_gather_fused<false, false><<<NB_GA2, 256, 0, stream>>>(
        g16a, colp, fill, bs_ + 3 * HID,
        bn_g + 4 * HID, bn_b + 4 * HID, bn_m + 4 * HID, bn_v + 4 * HID,
        nullptr, h4, nullptr, nullptr);

    // pool + final
    k_poolfinal<<<N_GRAPHS, 1024, 0, stream>>>(h, batch, lin_w, lin_b, out);
}